// Round 1
// baseline (1395.248 us; speedup 1.0000x reference)
//
#include <hip/hip_runtime.h>
#include <hip/hip_bf16.h>

typedef __attribute__((ext_vector_type(8))) short   short8;
typedef __attribute__((ext_vector_type(4))) float   floatx4;
typedef __attribute__((ext_vector_type(4))) unsigned short ushort4v;

#define ICH 256

// ---------------- descriptors ----------------

struct Desc {
    int Wd[5];      // spatial size per scale (H==W)
    int BWd[5];     // tile width per scale
    int nbXd[5];    // x-blocks per scale
    int Moff[5];    // pixel offset of scale in fused act buffer
    int aoff[5];    // anchor offset of scale (9*Moff)
    int bstart[6];  // prefix sum of spatial blocks per scale
};

struct FeatPtrs { const float* f[5]; };

// ---------------- conversion kernels ----------------

// fused feats transpose: per batch n, all scales: [256][M] f32 -> [21824][256] bf16
__global__ __launch_bounds__(256)
void convert_feats_all(FeatPtrs fp, Desc d, __hip_bfloat16* __restrict__ out, int n) {
    __shared__ float t[64][65];
    const int p = blockIdx.x * 64;          // global fused pixel index of this chunk
    int sc = 0;
    while (sc < 4 && p >= d.Moff[sc + 1]) ++sc;
    const int M  = d.Wd[sc] * d.Wd[sc];
    const int p0 = p - d.Moff[sc];
    const float* ib = fp.f[sc] + (size_t)n * ICH * M;
    __hip_bfloat16* ob = out + (size_t)p * ICH;
    const int tid = threadIdx.x;
    const int lo = tid & 63, hi = tid >> 6;
    for (int c0 = 0; c0 < ICH; c0 += 64) {
        #pragma unroll
        for (int r = 0; r < 16; ++r) {
            int ic = hi + 4 * r;
            t[ic][lo] = ib[(size_t)(c0 + ic) * M + p0 + lo];
        }
        __syncthreads();
        #pragma unroll
        for (int r = 0; r < 16; ++r) {
            int pp = hi + 4 * r;
            ob[(size_t)pp * ICH + c0 + lo] = __float2bfloat16(t[lo][pp]);
        }
        __syncthreads();
    }
}

// mid weights: [4][256][256][9] f32 -> [4][9][256][256] bf16
__global__ __launch_bounds__(256)
void convert_wmid(const float* __restrict__ in, __hip_bfloat16* __restrict__ out) {
    int idx = blockIdx.x * 256 + threadIdx.x;   // 4*9*256*256 total
    int ic = idx & 255, r = idx >> 8;
    int oc = r & 255, r2 = r >> 8;              // r2 = l*9+s
    int s = r2 % 9, l = r2 / 9;
    out[idx] = __float2bfloat16(in[(size_t)((l * 256 + oc) * 256 + ic) * 9 + s]);
}

// final weights: [OC][256][9] f32 -> [9][OCpad][256] bf16 (zero-padded)
__global__ __launch_bounds__(256)
void convert_wfin(const float* __restrict__ in, __hip_bfloat16* __restrict__ out,
                  int OC, int OCpad) {
    int idx = blockIdx.x * 256 + threadIdx.x;   // 9*OCpad*256 total
    int ic = idx & 255, r = idx >> 8;
    int oc = r % OCpad, s = r / OCpad;
    float v = 0.0f;
    if (oc < OC) v = in[(size_t)(oc * 256 + ic) * 9 + s];
    out[idx] = __float2bfloat16(v);
}

// ---------------- fused MFMA conv kernel ----------------
// One launch covers: all 5 scales (blockIdx.x via Desc), oc blocks (blockIdx.y),
// both heads (mid: blockIdx.z; final: blockIdx.y==7 -> reg head).
// Batch element is fixed per launch (host pre-offsets pointers).
// act buffers: bf16 [21824][256] (ic contiguous), scale at pixel offset Moff[sc].
// weights: bf16 [9][OCL][256].
template<bool FINAL>
__global__ __launch_bounds__(256, 2)
void conv_fused(Desc d,
                const __hip_bfloat16* __restrict__ srcC,
                const __hip_bfloat16* __restrict__ srcR,
                const __hip_bfloat16* __restrict__ wC,
                const __hip_bfloat16* __restrict__ wR,
                const float* __restrict__ bC,
                const float* __restrict__ bR,
                __hip_bfloat16* __restrict__ dstC,
                __hip_bfloat16* __restrict__ dstR,
                float* __restrict__ foutC,
                float* __restrict__ foutR,
                int OCLc, int OCLr, int OCc, int OCr, int KOUTc, int KOUTr)
{
    constexpr int HTOT = 180;       // BWP*BHP: 18*10 == 10*18 for both tile shapes

    __shared__ short lds_act[HTOT * 64];
    __shared__ short lds_w[128 * 64];

    // resolve scale / tile position
    int bl = blockIdx.x, sc = 0;
    while (bl >= d.bstart[sc + 1]) ++sc;
    const int rb  = bl - d.bstart[sc];
    const int W   = d.Wd[sc], H = W;
    const int BW  = d.BWd[sc], BH = 128 / BW, BWP = BW + 2;
    const int nbX = d.nbXd[sc];
    const int by  = rb / nbX, bx = rb - by * nbX;
    const int y0  = by * BH, x0 = bx * BW;

    // resolve head / oc block
    int head, oc0;
    if constexpr (FINAL) {
        head = (blockIdx.y == 7) ? 1 : 0;
        oc0  = head ? 0 : blockIdx.y * 128;
    } else {
        head = blockIdx.z;
        oc0  = blockIdx.y * 128;
    }

    const __hip_bfloat16* actin = head ? srcR : srcC;
    const __hip_bfloat16* wsrc  = head ? wR : wC;
    const float*          bias  = head ? bR : bC;
    const int             OCL   = head ? OCLr : OCLc;

    const int tid  = threadIdx.x;
    const int lane = tid & 63, wv = tid >> 6;
    const int mw = wv >> 1, nw = wv & 1;
    const int ln = lane & 15, q = lane >> 4;
    const int sub = tid & 7, grp = tid >> 3;    // 0..7, 0..31

    const short* actg = (const short*)actin + (size_t)d.Moff[sc] * ICH;
    const short* wg   = (const short*)wsrc;

    int base_a[4], base_b[4];
    #pragma unroll
    for (int j = 0; j < 4; ++j)
        base_a[j] = (mw * 64 + 16 * j + ln) * 64 + q * 8;
    #pragma unroll
    for (int i = 0; i < 4; ++i) {
        int t  = nw * 64 + 16 * i + ln;
        int ty = t / BW, tx = t - ty * BW;
        base_b[i] = ((ty + 1) * BWP + tx + 1) * 64 + q * 8;
    }

    floatx4 acc[4][4] = {};

    short8 wreg[4];
    auto loadw = [&](int s, int icb) {
        #pragma unroll
        for (int it = 0; it < 4; ++it) {
            int ocl = grp + 32 * it;
            wreg[it] = *(const short8*)(wg + ((size_t)(s * OCL + oc0 + ocl) * ICH
                                              + icb * 64 + sub * 8));
        }
    };

    loadw(0, 0);

    for (int icb = 0; icb < 4; ++icb) {
        // stage activation halo tile (180 px x 64 ic) for this channel block
        #pragma unroll
        for (int it = 0; it < 6; ++it) {
            int hp = grp + 32 * it;
            if (hp < HTOT) {
                int hy = hp / BWP, hx = hp - hy * BWP;
                int gy = y0 - 1 + hy, gx = x0 - 1 + hx;
                short8 v = {};
                if ((unsigned)gy < (unsigned)H && (unsigned)gx < (unsigned)W)
                    v = *(const short8*)(actg + ((size_t)(gy * W + gx) * ICH
                                                 + icb * 64 + sub * 8));
                *(short8*)(&lds_act[hp * 64 + sub * 8]) = v;
            }
        }
        #pragma unroll
        for (int s = 0; s < 9; ++s) {
            // write prefetched weight tile to LDS
            #pragma unroll
            for (int it = 0; it < 4; ++it)
                *(short8*)(&lds_w[(grp + 32 * it) * 64 + sub * 8]) = wreg[it];
            __syncthreads();
            // prefetch next weight tile (overlaps with MFMA below)
            if (s < 8)          loadw(s + 1, icb);
            else if (icb < 3)   loadw(0, icb + 1);

            const int dy = s / 3 - 1, dx = s % 3 - 1;
            const int soff = (dy * BWP + dx) * 64;
            #pragma unroll
            for (int kk = 0; kk < 2; ++kk) {
                short8 af[4], bf[4];
                #pragma unroll
                for (int j = 0; j < 4; ++j)
                    af[j] = *(const short8*)(&lds_w[base_a[j] + 32 * kk]);
                #pragma unroll
                for (int i = 0; i < 4; ++i)
                    bf[i] = *(const short8*)(&lds_act[base_b[i] + soff + 32 * kk]);
                #pragma unroll
                for (int j = 0; j < 4; ++j)
                    #pragma unroll
                    for (int i = 0; i < 4; ++i)
                        acc[j][i] = __builtin_amdgcn_mfma_f32_16x16x32_bf16(
                            af[j], bf[i], acc[j][i], 0, 0, 0);
            }
            __syncthreads();
        }
    }

    // ---------------- epilogue ----------------
    if constexpr (!FINAL) {
        __hip_bfloat16* ob = (head ? dstR : dstC) + (size_t)d.Moff[sc] * ICH;
        #pragma unroll
        for (int j = 0; j < 4; ++j) {
            int oc = oc0 + mw * 64 + 16 * j + q * 4;
            float bv[4];
            #pragma unroll
            for (int r = 0; r < 4; ++r) bv[r] = bias[oc + r];
            #pragma unroll
            for (int i = 0; i < 4; ++i) {
                int t  = nw * 64 + 16 * i + ln;
                int ty = t / BW, tx = t - ty * BW;
                int gy = y0 + ty;
                if (gy < H) {
                    union { ushort4v v; __hip_bfloat16 h[4]; } u;
                    #pragma unroll
                    for (int r = 0; r < 4; ++r)
                        u.h[r] = __float2bfloat16(fmaxf(acc[j][i][r] + bv[r], 0.0f));
                    *(ushort4v*)(ob + (size_t)(gy * W + x0 + tx) * ICH + oc) = u.v;
                }
            }
        }
    } else {
        const int KOUT = head ? KOUTr : KOUTc;
        const int OC   = head ? OCr : OCc;
        float* fb      = head ? foutR : foutC;
        const int aoff = d.aoff[sc];
        #pragma unroll
        for (int j = 0; j < 4; ++j) {
            int ocb = oc0 + mw * 64 + 16 * j + q * 4;
            #pragma unroll
            for (int i = 0; i < 4; ++i) {
                int t  = nw * 64 + 16 * i + ln;
                int ty = t / BW, tx = t - ty * BW;
                int gy = y0 + ty;
                if (gy < H) {
                    int p = gy * W + x0 + tx;
                    #pragma unroll
                    for (int r = 0; r < 4; ++r) {
                        int oc = ocb + r;
                        if (oc < OC) {
                            int a = oc / KOUT, c = oc - a * KOUT;
                            fb[(size_t)(aoff + p * 9 + a) * KOUT + c] =
                                acc[j][i][r] + bias[oc];
                        }
                    }
                }
            }
        }
    }
}

// ---------------- host ----------------

extern "C" void kernel_launch(void* const* d_in, const int* in_sizes, int n_in,
                              void* d_out, int out_size, void* d_ws, size_t ws_size,
                              hipStream_t stream) {
    const float* feats[5];
    for (int i = 0; i < 5; i++) feats[i] = (const float*)d_in[i];
    const float* cls_conv_w = (const float*)d_in[5];
    const float* cls_conv_b = (const float*)d_in[6];
    const float* cls_out_w  = (const float*)d_in[7];
    const float* cls_out_b  = (const float*)d_in[8];
    const float* reg_conv_w = (const float*)d_in[9];
    const float* reg_conv_b = (const float*)d_in[10];
    const float* reg_out_w  = (const float*)d_in[11];
    const float* reg_out_b  = (const float*)d_in[12];

    const int MTOT = 21824;            // sum of H*W over scales
    const int ATOT = 196416;           // 9*MTOT

    // workspace layout (58.85 MB total; previous session verified >= 67 MB available)
    char* wp = (char*)d_ws;
    const size_t ABUF = (size_t)MTOT * ICH * 2;    // 11,173,888 B per act buffer
    __hip_bfloat16* featC = (__hip_bfloat16*)wp; wp += ABUF;
    __hip_bfloat16* actA0 = (__hip_bfloat16*)wp; wp += ABUF;
    __hip_bfloat16* actB0 = (__hip_bfloat16*)wp; wp += ABUF;
    __hip_bfloat16* actA1 = (__hip_bfloat16*)wp; wp += ABUF;
    __hip_bfloat16* wmid0 = (__hip_bfloat16*)wp; wp += (size_t)4 * 9 * 256 * 256 * 2;
    __hip_bfloat16* wmid1 = (__hip_bfloat16*)wp; wp += (size_t)4 * 9 * 256 * 256 * 2;
    __hip_bfloat16* wfc   = (__hip_bfloat16*)wp; wp += (size_t)9 * 896 * 256 * 2;
    __hip_bfloat16* wfr   = (__hip_bfloat16*)wp; wp += (size_t)9 * 128 * 256 * 2;

    // one-time weight conversions
    convert_wmid<<<4 * 9 * 256, 256, 0, stream>>>(cls_conv_w, wmid0);
    convert_wmid<<<4 * 9 * 256, 256, 0, stream>>>(reg_conv_w, wmid1);
    convert_wfin<<<9 * 896, 256, 0, stream>>>(cls_out_w, wfc, 819, 896);
    convert_wfin<<<9 * 128, 256, 0, stream>>>(reg_out_w, wfr, 36, 128);

    static const Desc d = {
        {128, 64, 32, 16, 8},                   // Wd
        {16, 16, 16, 16, 8},                    // BWd
        {8, 4, 2, 1, 1},                        // nbXd
        {0, 16384, 20480, 21504, 21760},        // Moff
        {0, 147456, 184320, 193536, 195840},    // aoff
        {0, 128, 160, 168, 170, 171}            // bstart
    };
    const int NBLK = 171;

    FeatPtrs fp;
    for (int i = 0; i < 5; i++) fp.f[i] = feats[i];

    float* cls_out = (float*)d_out;
    float* reg_out = (float*)d_out + (size_t)2 * ATOT * 91;

    // activation chains per batch element:
    //   cls: featC -> A0 -> B0 -> A0 -> B0 -> final
    //   reg: featC -> A1 -> featC -> A1 -> featC -> final
    const __hip_bfloat16* srcsC[4] = { featC, actA0, actB0, actA0 };
    __hip_bfloat16*       dstsC[4] = { actA0, actB0, actA0, actB0 };
    const __hip_bfloat16* srcsR[4] = { featC, actA1, featC, actA1 };
    __hip_bfloat16*       dstsR[4] = { actA1, featC, actA1, featC };

    for (int n = 0; n < 2; ++n) {
        convert_feats_all<<<dim3(MTOT / 64), 256, 0, stream>>>(fp, d, featC, n);

        for (int l = 0; l < 4; ++l) {
            conv_fused<false><<<dim3(NBLK, 2, 2), 256, 0, stream>>>(
                d, srcsC[l], srcsR[l],
                wmid0 + (size_t)l * 9 * 256 * 256, wmid1 + (size_t)l * 9 * 256 * 256,
                cls_conv_b + l * 256, reg_conv_b + l * 256,
                dstsC[l], dstsR[l], nullptr, nullptr,
                256, 256, 256, 256, 1, 1);
        }

        conv_fused<true><<<dim3(NBLK, 8, 1), 256, 0, stream>>>(
            d, actB0, featC,
            wfc, wfr, cls_out_b, reg_out_b,
            nullptr, nullptr,
            cls_out + (size_t)n * ATOT * 91, reg_out + (size_t)n * ATOT * 4,
            896, 128, 819, 36, 91, 4);
    }
}